// Round 7
// baseline (141.676 us; speedup 1.0000x reference)
//
#include <hip/hip_runtime.h>

#define HW   4096
#define HIMG 64
#define WIMG 64
#define CC   256
#define CR   32
#define B_   8

typedef __attribute__((ext_vector_type(8))) short bf16x8;
typedef __attribute__((ext_vector_type(4))) float f32x4;

__device__ inline unsigned short f2bf(float f) {
    union { float f; unsigned u; } v; v.f = f;
    return (unsigned short)((v.u + 0x8000u) >> 16);
}
__device__ inline float bf2f(unsigned short h) {
    union { unsigned u; float f; } v; v.u = ((unsigned)h) << 16; return v.f;
}
__device__ inline unsigned pack2(float a, float b) {
    return (unsigned)f2bf(a) | ((unsigned)f2bf(b) << 16);
}
// XCD-contiguous h mapping: XCD i owns h in [8i, 8i+8). Used by ALL kernels
// so producer row-h writes and consumer row-h (and h±1 halo) reads land on
// the same XCD's L2.
__device__ inline int hswz(int hx) { return ((hx & 7) << 3) | (hx >> 3); }

// ---------------------------------------------------------------------------
// K1: weights -> bf16, concat [Wq;Wk;Wv] into Wb[320][256]; biases into bb.
// ---------------------------------------------------------------------------
__global__ __launch_bounds__(256) void wconv(
    const float* __restrict__ Wq, const float* __restrict__ bq,
    const float* __restrict__ Wk, const float* __restrict__ bk,
    const float* __restrict__ Wv, const float* __restrict__ bv,
    unsigned short* __restrict__ Wb, float* __restrict__ bb)
{
    const int o = blockIdx.x;   // 0..319
    const float* src; const float* bsrc; int orel;
    if (o < 32)      { src = Wq; bsrc = bq; orel = o;      }
    else if (o < 64) { src = Wk; bsrc = bk; orel = o - 32; }
    else             { src = Wv; bsrc = bv; orel = o - 64; }
    Wb[o * CC + threadIdx.x] = f2bf(src[orel * CC + threadIdx.x]);
    if (threadIdx.x == 0) bb[o] = bsrc[orel];
}

// ---------------------------------------------------------------------------
// K2: transpose+convert+GEMM.  Base = R5 (As in LDS — R6 proved the L2 path
// regresses).  CHANGED vs R5:
//  (a) x-stage pipelined through registers (T14): chunk kc+1's 4 float4
//      loads are ISSUED during chunk kc's MFMA phase (MFMA reads only
//      As/Bs, never xt32) and written to LDS after the next barrier.
//      Removes ~900cy HBM latency from the per-chunk critical path.
//  (b) h-swizzle on blockIdx.x for cross-kernel XCD-L2 locality.
// Arithmetic/layout byte-identical to R5.
// ---------------------------------------------------------------------------
__global__ __launch_bounds__(256) void proj_gemm(
    const unsigned short* __restrict__ Wb, const float* __restrict__ bb,
    const float* __restrict__ x,
    float* __restrict__ q, float* __restrict__ k,
    unsigned short* __restrict__ vv)
{
    __shared__ unsigned short As[320 * 72];
    __shared__ float          xt32[64 * 65];
    __shared__ unsigned short Bs[64 * 64];

    const int b   = blockIdx.y;
    const int hw0 = hswz(blockIdx.x) * 64;
    const int t    = threadIdx.x;
    const int lane = t & 63, wv = t >> 6;
    const int m16  = lane & 15, quad = lane >> 4;

    f32x4 acc[5][4];
    #pragma unroll
    for (int i = 0; i < 5; ++i)
        #pragma unroll
        for (int n = 0; n < 4; ++n)
            acc[i][n] = (f32x4){0.f, 0.f, 0.f, 0.f};

    // per-thread x-stage coordinates (fixed across chunks)
    const int xc  = t >> 4;             // 0..15 -> channel offset within chunk
    const int xp4 = (t & 15) * 4;       // px offset
    const float* xbase = &x[((size_t)b * CC + xc) * HW + hw0 + xp4];

    // prefetch chunk 0
    float4 xp[4];
    #pragma unroll
    for (int i = 0; i < 4; ++i)
        xp[i] = *(const float4*)&xbase[(size_t)(16 * i) * HW];

    for (int kc = 0; kc < 4; ++kc) {
        const int k0 = kc * 64;
        if (kc) __syncthreads();            // prev MFMA/transpose done

        // write prefetched x regs -> xt32 (LDS-only, no HBM latency here)
        #pragma unroll
        for (int i = 0; i < 4; ++i)
            *(float4*)&xt32[(xc + 16 * i) * 65 + xp4] = xp[i];

        // stage A: 320 rows x 64 k bf16 (L2-resident Wb)
        #pragma unroll
        for (int i = 0; i < 10; ++i) {
            int idx = t + 256 * i;          // 0..2559
            int row = idx >> 3, s8 = idx & 7;
            *(uint4*)&As[row * 72 + s8 * 8] =
                *(const uint4*)&Wb[row * CC + k0 + s8 * 8];
        }
        __syncthreads();

        // transpose+convert into Bs: thread -> px = lane, 16 channels
        {
            const int px = lane;
            const int c0 = wv * 16;
            float f[16];
            #pragma unroll
            for (int j = 0; j < 16; ++j)
                f[j] = xt32[(c0 + j) * 65 + px];   // bank (c0+j+px)%32: 2-way
            uint4 w0, w1;
            w0.x = pack2(f[0],  f[1]);  w0.y = pack2(f[2],  f[3]);
            w0.z = pack2(f[4],  f[5]);  w0.w = pack2(f[6],  f[7]);
            w1.x = pack2(f[8],  f[9]);  w1.y = pack2(f[10], f[11]);
            w1.z = pack2(f[12], f[13]); w1.w = pack2(f[14], f[15]);
            const int lg0 = c0 >> 3, sw = px & 7;
            *(uint4*)&Bs[px * 64 + ((lg0     ^ sw) * 8)] = w0;
            *(uint4*)&Bs[px * 64 + (((lg0+1) ^ sw) * 8)] = w1;
        }
        __syncthreads();

        // issue next chunk's x loads BEFORE the MFMA phase: the ~900cy HBM
        // latency completes while MFMA/ds_reads execute.
        if (kc < 3) {
            #pragma unroll
            for (int i = 0; i < 4; ++i)
                xp[i] = *(const float4*)&xbase[(size_t)(k0 + 64 + 16 * i) * HW];
        }

        #pragma unroll
        for (int ks = 0; ks < 2; ++ks) {
            bf16x8 af[5], bf[4];
            #pragma unroll
            for (int i = 0; i < 5; ++i)
                af[i] = *(const bf16x8*)&As[((wv * 5 + i) * 16 + m16) * 72
                                            + ks * 32 + quad * 8];
            #pragma unroll
            for (int n = 0; n < 4; ++n) {
                int px = n * 16 + m16;
                int lg = ks * 4 + quad;
                bf[n] = *(const bf16x8*)&Bs[px * 64 + ((lg ^ (px & 7)) * 8)];
            }
            #pragma unroll
            for (int i = 0; i < 5; ++i)
                #pragma unroll
                for (int n = 0; n < 4; ++n)
                    acc[i][n] = __builtin_amdgcn_mfma_f32_16x16x32_bf16(
                        af[i], bf[n], acc[i][n], 0, 0, 0);
        }
    }

    // epilogue: D row = quad*4+reg, col = lane&15
    #pragma unroll
    for (int i = 0; i < 5; ++i) {
        const int ob = (wv * 5 + i) * 16;        // 0..304, wave-uniform
        #pragma unroll
        for (int r = 0; r < 4; ++r) {
            const int orow = quad * 4 + r;
            const float bias = bb[ob + orow];
            if (ob < 64) {                        // q or k, fp32
                float* dst = (ob < 32) ? q : k;
                int orel = (ob < 32) ? ob : ob - 32;
                size_t rowbase = ((size_t)b * CR + orel + orow) * HW;
                #pragma unroll
                for (int n = 0; n < 4; ++n)
                    dst[rowbase + hw0 + n * 16 + m16] = acc[i][n][r] + bias;
            } else {                              // v, bf16
                size_t rowbase = ((size_t)b * CC + (ob - 64) + orow) * HW;
                #pragma unroll
                for (int n = 0; n < 4; ++n)
                    vv[rowbase + hw0 + n * 16 + m16] = f2bf(acc[i][n][r] + bias);
            }
        }
    }
}

// ---------------------------------------------------------------------------
// K3: energies + softmax -> aw[b][hw][12].
// CHANGED vs R5: h-swizzle only (XCD-L2 locality with proj/apply).
// ---------------------------------------------------------------------------
__global__ __launch_bounds__(256) void attn_w(
    const float* __restrict__ q_, const float* __restrict__ k_,
    float* __restrict__ aw)
{
    __shared__ float qs[64][33];
    __shared__ float ks[3][64][33];
    __shared__ float es[64][9];
    const int h = hswz(blockIdx.x), b = blockIdx.y, t = threadIdx.x;

    #pragma unroll
    for (int i = 0; i < 2; ++i) {
        int idx = t + 256 * i, cr = idx >> 4, p4 = (idx & 15) * 4;
        float4 vq = *(const float4*)&q_[((size_t)b * CR + cr) * HW + h * WIMG + p4];
        qs[p4 + 0][cr] = vq.x; qs[p4 + 1][cr] = vq.y;
        qs[p4 + 2][cr] = vq.z; qs[p4 + 3][cr] = vq.w;
    }
    #pragma unroll
    for (int r = 0; r < 3; ++r) {
        int hh = h + r - 1;
        bool ok = (hh >= 0) && (hh < HIMG);
        #pragma unroll
        for (int i = 0; i < 2; ++i) {
            int idx = t + 256 * i, cr = idx >> 4, p4 = (idx & 15) * 4;
            float4 vk = make_float4(0.f, 0.f, 0.f, 0.f);
            if (ok)
                vk = *(const float4*)&k_[((size_t)b * CR + cr) * HW + hh * WIMG + p4];
            ks[r][p4 + 0][cr] = vk.x; ks[r][p4 + 1][cr] = vk.y;
            ks[r][p4 + 2][cr] = vk.z; ks[r][p4 + 3][cr] = vk.w;
        }
    }
    __syncthreads();

    for (int id = t; id < 576; id += 256) {
        int px = id / 9, kk = id - px * 9;
        int di = kk / 3, dj = kk - di * 3;
        int hh = h + di - 1, ww = px + dj - 1;
        float e = 0.f;
        if (hh >= 0 && hh < HIMG && ww >= 0 && ww < WIMG) {
            float s = 0.f;
            #pragma unroll
            for (int c = 0; c < CR; ++c) s = fmaf(qs[px][c], ks[di][ww][c], s);
            e = s;
        }
        es[px][kk] = e;
    }
    __syncthreads();

    if (t < 64) {
        float m = es[t][0];
        #pragma unroll
        for (int kk = 1; kk < 9; ++kk) m = fmaxf(m, es[t][kk]);
        float ex[9]; float ssum = 0.f;
        #pragma unroll
        for (int kk = 0; kk < 9; ++kk) { ex[kk] = __expf(es[t][kk] - m); ssum += ex[kk]; }
        float inv = 1.f / ssum;
        float* dst = &aw[((size_t)b * HW + h * WIMG + t) * 12];
        #pragma unroll
        for (int kk = 0; kk < 9; ++kk) dst[kk] = ex[kk] * inv;
    }
}

// ---------------------------------------------------------------------------
// K4: apply weights to v (bf16) + residual.  Base = R5 (odd strides 73/13,
// scalar LDS, conflict-free).  CHANGED vs R5:
//  (a) residual x float4 loads hoisted to kernel start (were tail-serialized
//      dependent loads after all compute; now hide under staging).
//  (b) h-swizzle (same mapping as proj/attn_w) -> vv/aw reads are XCD-L2 hits.
// ---------------------------------------------------------------------------
__global__ __launch_bounds__(256) void apply(
    const float* __restrict__ x, const unsigned short* __restrict__ vv,
    const float* __restrict__ aw, const float* __restrict__ gamma,
    float* __restrict__ out)
{
    __shared__ float vs[3][32][73];   // [row][ch][4 zero | 64 px | 4 zero | 1 pad]
    __shared__ float aws[64][13];
    const int h = hswz(blockIdx.x), cb = blockIdx.y, b = blockIdx.z, t = threadIdx.x;

    // (a) residual prefetch — issued first, consumed last
    const int px0 = (t & 15) * 4;
    const int cl  = t >> 4;
    float4 xa[2]; size_t basec[2];
    #pragma unroll
    for (int ci = 0; ci < 2; ++ci) {
        int c = cl + 16 * ci;
        basec[ci] = ((size_t)b * CC + cb * 32 + c) * HW + h * WIMG + px0;
        xa[ci] = *(const float4*)&x[basec[ci]];
    }

    for (int p = t; p < 768; p += 256) {
        int px = p / 12, kk = p - px * 12;
        aws[px][kk] = aw[((size_t)b * HW + h * WIMG) * 12 + p];
    }
    #pragma unroll
    for (int i = 0; i < 6; ++i) {
        int idx = t + 256 * i;          // 0..1535
        int p4 = (idx & 15) * 4, c = (idx >> 4) & 31, r = idx >> 9;
        int hh = h + r - 1;
        float4 val = make_float4(0.f, 0.f, 0.f, 0.f);
        if (hh >= 0 && hh < HIMG) {
            ushort4 u = *(const ushort4*)&vv[((size_t)b * CC + cb * 32 + c) * HW
                                             + hh * WIMG + p4];
            val = make_float4(bf2f(u.x), bf2f(u.y), bf2f(u.z), bf2f(u.w));
        }
        float* dstp = &vs[r][c][4 + p4];
        dstp[0] = val.x; dstp[1] = val.y; dstp[2] = val.z; dstp[3] = val.w;
    }
    if (t < 96) {
        int r = t >> 5, c = t & 31;
        float* row = &vs[r][c][0];
        row[0] = 0.f; row[1] = 0.f; row[2] = 0.f; row[3] = 0.f;
        row[68] = 0.f; row[69] = 0.f; row[70] = 0.f; row[71] = 0.f;
    }
    __syncthreads();

    float w[4][9];
    #pragma unroll
    for (int i = 0; i < 4; ++i)
        #pragma unroll
        for (int kk = 0; kk < 9; ++kk) w[i][kk] = aws[px0 + i][kk];
    const float g = gamma[0];

    #pragma unroll
    for (int ci = 0; ci < 2; ++ci) {
        int c = cl + 16 * ci;
        float a0 = 0.f, a1 = 0.f, a2 = 0.f, a3 = 0.f;
        #pragma unroll
        for (int r = 0; r < 3; ++r) {
            const float* row = &vs[r][c][0];
            float lft = row[3 + px0];
            float c0  = row[4 + px0];
            float c1  = row[5 + px0];
            float c2  = row[6 + px0];
            float c3  = row[7 + px0];
            float rgt = row[8 + px0];
            int r3 = r * 3;
            a0 = fmaf(w[0][r3], lft, fmaf(w[0][r3+1], c0, fmaf(w[0][r3+2], c1, a0)));
            a1 = fmaf(w[1][r3], c0,  fmaf(w[1][r3+1], c1, fmaf(w[1][r3+2], c2, a1)));
            a2 = fmaf(w[2][r3], c1,  fmaf(w[2][r3+1], c2, fmaf(w[2][r3+2], c3, a2)));
            a3 = fmaf(w[3][r3], c2,  fmaf(w[3][r3+1], c3, fmaf(w[3][r3+2], rgt, a3)));
        }
        float4 o;
        o.x = fmaf(g, a0, xa[ci].x); o.y = fmaf(g, a1, xa[ci].y);
        o.z = fmaf(g, a2, xa[ci].z); o.w = fmaf(g, a3, xa[ci].w);
        *(float4*)&out[basec[ci]] = o;
    }
}

extern "C" void kernel_launch(void* const* d_in, const int* in_sizes, int n_in,
                              void* d_out, int out_size, void* d_ws, size_t ws_size,
                              hipStream_t stream)
{
    const float* x     = (const float*)d_in[0];
    const float* Wq    = (const float*)d_in[1];
    const float* bq    = (const float*)d_in[2];
    const float* Wk    = (const float*)d_in[3];
    const float* bk    = (const float*)d_in[4];
    const float* Wv    = (const float*)d_in[5];
    const float* bv    = (const float*)d_in[6];
    const float* gamma = (const float*)d_in[7];
    float* out = (float*)d_out;

    float* q  = (float*)d_ws;                                  //  4.19 MB
    float* k  = q + (size_t)B_ * CR * HW;                      //  4.19 MB
    unsigned short* vv = (unsigned short*)(k + (size_t)B_ * CR * HW); // 16.78 MB
    float* aw = (float*)(vv + (size_t)B_ * CC * HW);           //  1.57 MB
    unsigned short* Wb = (unsigned short*)(aw + (size_t)B_ * HW * 12); // 160 KB
    float* bb = (float*)(Wb + 320 * CC);

    wconv<<<dim3(320), 256, 0, stream>>>(Wq, bq, Wk, bk, Wv, bv, Wb, bb);
    proj_gemm<<<dim3(HW / 64, B_), 256, 0, stream>>>(Wb, bb, x, q, k, vv);
    attn_w<<<dim3(HIMG, B_), 256, 0, stream>>>(q, k, aw);
    apply<<<dim3(HIMG, CC / 32, B_), 256, 0, stream>>>(x, vv, aw, gamma, out);
}

// Round 9
// 128.795 us; speedup vs baseline: 1.1000x; 1.1000x over previous
//
#include <hip/hip_runtime.h>

#define HW   4096
#define HIMG 64
#define WIMG 64
#define CC   256
#define CR   32
#define B_   8

typedef __attribute__((ext_vector_type(8))) short bf16x8;
typedef __attribute__((ext_vector_type(4))) float f32x4;

__device__ inline unsigned short f2bf(float f) {
    union { float f; unsigned u; } v; v.f = f;
    return (unsigned short)((v.u + 0x8000u) >> 16);
}
__device__ inline float bf2f(unsigned short h) {
    union { unsigned u; float f; } v; v.u = ((unsigned)h) << 16; return v.f;
}
__device__ inline unsigned pack2(float a, float b) {
    return (unsigned)f2bf(a) | ((unsigned)f2bf(b) << 16);
}

// ---------------------------------------------------------------------------
// K1: weights -> bf16, concat [Wq;Wk;Wv] into Wb[320][256]; biases into bb.
// (byte-identical to R5)
// ---------------------------------------------------------------------------
__global__ __launch_bounds__(256) void wconv(
    const float* __restrict__ Wq, const float* __restrict__ bq,
    const float* __restrict__ Wk, const float* __restrict__ bk,
    const float* __restrict__ Wv, const float* __restrict__ bv,
    unsigned short* __restrict__ Wb, float* __restrict__ bb)
{
    const int o = blockIdx.x;   // 0..319
    const float* src; const float* bsrc; int orel;
    if (o < 32)      { src = Wq; bsrc = bq; orel = o;      }
    else if (o < 64) { src = Wk; bsrc = bk; orel = o - 32; }
    else             { src = Wv; bsrc = bv; orel = o - 64; }
    Wb[o * CC + threadIdx.x] = f2bf(src[orel * CC + threadIdx.x]);
    if (threadIdx.x == 0) bb[o] = bsrc[orel];
}

// ---------------------------------------------------------------------------
// K2: fused transpose+convert+GEMM.  (byte-identical to R5, the 131.7µs best)
// ---------------------------------------------------------------------------
__global__ __launch_bounds__(256) void proj_gemm(
    const unsigned short* __restrict__ Wb, const float* __restrict__ bb,
    const float* __restrict__ x,
    float* __restrict__ q, float* __restrict__ k,
    unsigned short* __restrict__ vv)
{
    __shared__ unsigned short As[320 * 72];
    __shared__ float          xt32[64 * 65];
    __shared__ unsigned short Bs[64 * 64];

    const int b   = blockIdx.y;
    const int hw0 = blockIdx.x * 64;
    const int t    = threadIdx.x;
    const int lane = t & 63, wv = t >> 6;
    const int m16  = lane & 15, quad = lane >> 4;

    f32x4 acc[5][4];
    #pragma unroll
    for (int i = 0; i < 5; ++i)
        #pragma unroll
        for (int n = 0; n < 4; ++n)
            acc[i][n] = (f32x4){0.f, 0.f, 0.f, 0.f};

    for (int kc = 0; kc < 4; ++kc) {
        const int k0 = kc * 64;
        if (kc) __syncthreads();            // protect As/xt32/Bs reuse

        // stage A: 320 rows x 64 k bf16 (L2-resident W)
        #pragma unroll
        for (int i = 0; i < 10; ++i) {
            int idx = t + 256 * i;          // 0..2559
            int row = idx >> 3, s8 = idx & 7;
            *(uint4*)&As[row * 72 + s8 * 8] =
                *(const uint4*)&Wb[row * CC + k0 + s8 * 8];
        }
        // stage x chunk fp32: 64 c x 64 px, coalesced along px
        #pragma unroll
        for (int i = 0; i < 4; ++i) {
            int idx = t + 256 * i;          // 0..1023
            int c = idx >> 4, p4 = (idx & 15) * 4;
            float4 vx = *(const float4*)&x[((size_t)b * CC + k0 + c) * HW + hw0 + p4];
            *(float4*)&xt32[c * 65 + p4] = vx;
        }
        __syncthreads();

        // transpose+convert into Bs: thread -> px = lane, 16 channels
        {
            const int px = lane;
            const int c0 = wv * 16;
            float f[16];
            #pragma unroll
            for (int j = 0; j < 16; ++j)
                f[j] = xt32[(c0 + j) * 65 + px];   // bank (c0+j+px)%32: 2-way
            uint4 w0, w1;
            w0.x = pack2(f[0],  f[1]);  w0.y = pack2(f[2],  f[3]);
            w0.z = pack2(f[4],  f[5]);  w0.w = pack2(f[6],  f[7]);
            w1.x = pack2(f[8],  f[9]);  w1.y = pack2(f[10], f[11]);
            w1.z = pack2(f[12], f[13]); w1.w = pack2(f[14], f[15]);
            const int lg0 = c0 >> 3, sw = px & 7;
            *(uint4*)&Bs[px * 64 + ((lg0     ^ sw) * 8)] = w0;
            *(uint4*)&Bs[px * 64 + (((lg0+1) ^ sw) * 8)] = w1;
        }
        __syncthreads();

        #pragma unroll
        for (int ks = 0; ks < 2; ++ks) {
            bf16x8 af[5], bf[4];
            #pragma unroll
            for (int i = 0; i < 5; ++i)
                af[i] = *(const bf16x8*)&As[((wv * 5 + i) * 16 + m16) * 72
                                            + ks * 32 + quad * 8];
            #pragma unroll
            for (int n = 0; n < 4; ++n) {
                int px = n * 16 + m16;
                int lg = ks * 4 + quad;
                bf[n] = *(const bf16x8*)&Bs[px * 64 + ((lg ^ (px & 7)) * 8)];
            }
            #pragma unroll
            for (int i = 0; i < 5; ++i)
                #pragma unroll
                for (int n = 0; n < 4; ++n)
                    acc[i][n] = __builtin_amdgcn_mfma_f32_16x16x32_bf16(
                        af[i], bf[n], acc[i][n], 0, 0, 0);
        }
    }

    // epilogue: D row = quad*4+reg, col = lane&15
    #pragma unroll
    for (int i = 0; i < 5; ++i) {
        const int ob = (wv * 5 + i) * 16;        // 0..304, wave-uniform
        #pragma unroll
        for (int r = 0; r < 4; ++r) {
            const int orow = quad * 4 + r;
            const float bias = bb[ob + orow];
            if (ob < 64) {                        // q or k, fp32
                float* dst = (ob < 32) ? q : k;
                int orel = (ob < 32) ? ob : ob - 32;
                size_t rowbase = ((size_t)b * CR + orel + orow) * HW;
                #pragma unroll
                for (int n = 0; n < 4; ++n)
                    dst[rowbase + hw0 + n * 16 + m16] = acc[i][n][r] + bias;
            } else {                              // v, bf16
                size_t rowbase = ((size_t)b * CC + (ob - 64) + orow) * HW;
                #pragma unroll
                for (int n = 0; n < 4; ++n)
                    vv[rowbase + hw0 + n * 16 + m16] = f2bf(acc[i][n][r] + bias);
            }
        }
    }
}

// ---------------------------------------------------------------------------
// K3: MERGED energies + softmax + apply + residual.  One block per (h, b),
// 512 threads.  Phase bodies use R5's verified arithmetic and the R5
// conflict-free LDS layouts (odd strides 33 / 73 / 13, scalar vs/aws traffic).
// aw never touches HBM; one launch boundary deleted.
// LDS: union{ qk-phase 36.1KB | vs 56.1KB } + aws 3.3KB = 59.4KB -> 2 blk/CU;
// grid 512 = exactly co-resident (no launch tail).
// ---------------------------------------------------------------------------
__global__ __launch_bounds__(512) void attn_apply(
    const float* __restrict__ q_, const float* __restrict__ k_,
    const unsigned short* __restrict__ vv,
    const float* __restrict__ x, const float* __restrict__ gamma,
    float* __restrict__ out)
{
    struct PA {
        float qs[64][33];     //  8448 B
        float ks[3][64][33];  // 25344 B
        float es[64][9];      //  2304 B
    };
    struct PV {
        float vs[3][64][73];  // 56064 B  [row][ch][4 zero | 64 px | 4 zero | 1]
    };
    __shared__ union USM { PA a; PV v; } sm;    // 56064 B
    __shared__ float aws[64][13];               //  3328 B (persistent)

    const int h = blockIdx.x, b = blockIdx.y, t = threadIdx.x;

    // ---- stage q + 3 k-rows (R5 attn_w layout, 2x lanes) ----
    {
        const int cr = t >> 4, p4 = (t & 15) * 4;   // 512 threads = 32cr x 16px4
        float4 vq = *(const float4*)&q_[((size_t)b * CR + cr) * HW + h * WIMG + p4];
        sm.a.qs[p4 + 0][cr] = vq.x; sm.a.qs[p4 + 1][cr] = vq.y;
        sm.a.qs[p4 + 2][cr] = vq.z; sm.a.qs[p4 + 3][cr] = vq.w;
        #pragma unroll
        for (int r = 0; r < 3; ++r) {
            int hh = h + r - 1;
            float4 vk = make_float4(0.f, 0.f, 0.f, 0.f);
            if (hh >= 0 && hh < HIMG)
                vk = *(const float4*)&k_[((size_t)b * CR + cr) * HW + hh * WIMG + p4];
            sm.a.ks[r][p4 + 0][cr] = vk.x; sm.a.ks[r][p4 + 1][cr] = vk.y;
            sm.a.ks[r][p4 + 2][cr] = vk.z; sm.a.ks[r][p4 + 3][cr] = vk.w;
        }
    }
    __syncthreads();

    // ---- energies (R5 arithmetic) ----
    for (int id = t; id < 576; id += 512) {
        int px = id / 9, kk = id - px * 9;
        int di = kk / 3, dj = kk - di * 3;
        int hh = h + di - 1, ww = px + dj - 1;
        float e = 0.f;
        if (hh >= 0 && hh < HIMG && ww >= 0 && ww < WIMG) {
            float s = 0.f;
            #pragma unroll
            for (int c = 0; c < CR; ++c)
                s = fmaf(sm.a.qs[px][c], sm.a.ks[di][ww][c], s);
            e = s;
        }
        sm.a.es[px][kk] = e;
    }
    __syncthreads();

    // ---- softmax -> aws (LDS only; R5 arithmetic) ----
    if (t < 64) {
        float m = sm.a.es[t][0];
        #pragma unroll
        for (int kk = 1; kk < 9; ++kk) m = fmaxf(m, sm.a.es[t][kk]);
        float ex[9]; float ssum = 0.f;
        #pragma unroll
        for (int kk = 0; kk < 9; ++kk) { ex[kk] = __expf(sm.a.es[t][kk] - m); ssum += ex[kk]; }
        float inv = 1.f / ssum;
        #pragma unroll
        for (int kk = 0; kk < 9; ++kk) aws[t][kk] = ex[kk] * inv;
    }
    __syncthreads();   // es reads done -> vs (overlapping a.*) may be written

    // ---- zero vs pads once (staging never touches them) ----
    if (t < 192) {
        int r = t / 64, c = t - r * 64;
        float* row = &sm.v.vs[r][c][0];
        row[0] = 0.f; row[1] = 0.f; row[2] = 0.f; row[3] = 0.f;
        row[68] = 0.f; row[69] = 0.f; row[70] = 0.f; row[71] = 0.f;
    }

    const int px0 = (t & 15) * 4;
    const int cl  = t >> 4;                 // 0..31
    const float g = gamma[0];
    float w[4][9];
    #pragma unroll
    for (int i = 0; i < 4; ++i)
        #pragma unroll
        for (int kk = 0; kk < 9; ++kk) w[i][kk] = aws[px0 + i][kk];

    // ---- 4 chunks of 64 channels (R5 apply body, stride-73 scalar LDS) ----
    for (int cb = 0; cb < 4; ++cb) {
        if (cb) __syncthreads();            // protect vs reuse
        #pragma unroll
        for (int i = 0; i < 6; ++i) {
            int idx = t + 512 * i;          // 0..3071
            int p4 = (idx & 15) * 4, c = (idx >> 4) & 63, r = idx >> 10;
            int hh = h + r - 1;
            float4 val = make_float4(0.f, 0.f, 0.f, 0.f);
            if (hh >= 0 && hh < HIMG) {
                ushort4 u = *(const ushort4*)&vv[((size_t)b * CC + cb * 64 + c) * HW
                                                 + hh * WIMG + p4];
                val = make_float4(bf2f(u.x), bf2f(u.y), bf2f(u.z), bf2f(u.w));
            }
            float* dstp = &sm.v.vs[r][c][4 + p4];
            dstp[0] = val.x; dstp[1] = val.y; dstp[2] = val.z; dstp[3] = val.w;
        }
        __syncthreads();

        #pragma unroll
        for (int ci = 0; ci < 2; ++ci) {
            int c = cl + 32 * ci;
            float a0 = 0.f, a1 = 0.f, a2 = 0.f, a3 = 0.f;
            #pragma unroll
            for (int r = 0; r < 3; ++r) {
                const float* row = &sm.v.vs[r][c][0];
                float lft = row[3 + px0];
                float c0  = row[4 + px0];
                float c1  = row[5 + px0];
                float c2  = row[6 + px0];
                float c3  = row[7 + px0];
                float rgt = row[8 + px0];
                int r3 = r * 3;
                a0 = fmaf(w[0][r3], lft, fmaf(w[0][r3+1], c0, fmaf(w[0][r3+2], c1, a0)));
                a1 = fmaf(w[1][r3], c0,  fmaf(w[1][r3+1], c1, fmaf(w[1][r3+2], c2, a1)));
                a2 = fmaf(w[2][r3], c1,  fmaf(w[2][r3+1], c2, fmaf(w[2][r3+2], c3, a2)));
                a3 = fmaf(w[3][r3], c2,  fmaf(w[3][r3+1], c3, fmaf(w[3][r3+2], rgt, a3)));
            }
            size_t base = ((size_t)b * CC + cb * 64 + c) * HW + h * WIMG + px0;
            float4 xa = *(const float4*)&x[base];
            float4 o;
            o.x = fmaf(g, a0, xa.x); o.y = fmaf(g, a1, xa.y);
            o.z = fmaf(g, a2, xa.z); o.w = fmaf(g, a3, xa.w);
            *(float4*)&out[base] = o;
        }
    }
}

extern "C" void kernel_launch(void* const* d_in, const int* in_sizes, int n_in,
                              void* d_out, int out_size, void* d_ws, size_t ws_size,
                              hipStream_t stream)
{
    const float* x     = (const float*)d_in[0];
    const float* Wq    = (const float*)d_in[1];
    const float* bq    = (const float*)d_in[2];
    const float* Wk    = (const float*)d_in[3];
    const float* bk    = (const float*)d_in[4];
    const float* Wv    = (const float*)d_in[5];
    const float* bv    = (const float*)d_in[6];
    const float* gamma = (const float*)d_in[7];
    float* out = (float*)d_out;

    float* q  = (float*)d_ws;                                  //  4.19 MB
    float* k  = q + (size_t)B_ * CR * HW;                      //  4.19 MB
    unsigned short* vv = (unsigned short*)(k + (size_t)B_ * CR * HW); // 16.78 MB
    unsigned short* Wb = vv + (size_t)B_ * CC * HW;            // 160 KB
    float* bb = (float*)(Wb + 320 * CC);

    wconv<<<dim3(320), 256, 0, stream>>>(Wq, bq, Wk, bk, Wv, bv, Wb, bb);
    proj_gemm<<<dim3(HW / 64, B_), 256, 0, stream>>>(Wb, bb, x, q, k, vv);
    attn_apply<<<dim3(HIMG, B_), 512, 0, stream>>>(q, k, vv, x, gamma, out);
}

// Round 10
// 128.226 us; speedup vs baseline: 1.1049x; 1.0044x over previous
//
#include <hip/hip_runtime.h>

#define HW   4096
#define HIMG 64
#define WIMG 64
#define CC   256
#define CR   32
#define B_   8

typedef __attribute__((ext_vector_type(8))) short bf16x8;
typedef __attribute__((ext_vector_type(4))) float f32x4;

__device__ inline unsigned short f2bf(float f) {
    union { float f; unsigned u; } v; v.f = f;
    return (unsigned short)((v.u + 0x8000u) >> 16);
}
__device__ inline float bf2f(unsigned short h) {
    union { unsigned u; float f; } v; v.u = ((unsigned)h) << 16; return v.f;
}
__device__ inline unsigned pack2(float a, float b) {
    return (unsigned)f2bf(a) | ((unsigned)f2bf(b) << 16);
}

// ---------------------------------------------------------------------------
// K1: fused transpose+convert+GEMM.  Base = R9's proj (the verified body).
// CHANGED: wconv kernel DELETED.  As staging reads Wq/Wk/Wv fp32 directly
// (L2-resident, 327 KB total) and applies the SAME f2bf inline -> bit-
// identical As contents, identical MFMA inputs.  Biases read directly in
// the epilogue.  One kernel + one graph boundary + the Wb round-trip gone.
// ---------------------------------------------------------------------------
__global__ __launch_bounds__(256) void proj_gemm(
    const float* __restrict__ Wq, const float* __restrict__ bq,
    const float* __restrict__ Wk, const float* __restrict__ bk,
    const float* __restrict__ Wv, const float* __restrict__ bv,
    const float* __restrict__ x,
    float* __restrict__ q, float* __restrict__ k,
    unsigned short* __restrict__ vv)
{
    __shared__ unsigned short As[320 * 72];
    __shared__ float          xt32[64 * 65];
    __shared__ unsigned short Bs[64 * 64];

    const int b   = blockIdx.y;
    const int hw0 = blockIdx.x * 64;
    const int t    = threadIdx.x;
    const int lane = t & 63, wv = t >> 6;
    const int m16  = lane & 15, quad = lane >> 4;

    f32x4 acc[5][4];
    #pragma unroll
    for (int i = 0; i < 5; ++i)
        #pragma unroll
        for (int n = 0; n < 4; ++n)
            acc[i][n] = (f32x4){0.f, 0.f, 0.f, 0.f};

    for (int kc = 0; kc < 4; ++kc) {
        const int k0 = kc * 64;
        if (kc) __syncthreads();            // protect As/xt32/Bs reuse

        // stage A: 320 rows x 64 ch, fp32 source -> bf16 inline (same f2bf)
        #pragma unroll
        for (int i = 0; i < 10; ++i) {
            int idx = t + 256 * i;          // 0..2559
            int row = idx >> 3, s8 = idx & 7;
            const float* wsrc = (row < 32) ? &Wq[row * CC]
                              : (row < 64) ? &Wk[(row - 32) * CC]
                                           : &Wv[(row - 64) * CC];
            float4 a0 = *(const float4*)&wsrc[k0 + s8 * 8];
            float4 a1 = *(const float4*)&wsrc[k0 + s8 * 8 + 4];
            uint4 u;
            u.x = pack2(a0.x, a0.y); u.y = pack2(a0.z, a0.w);
            u.z = pack2(a1.x, a1.y); u.w = pack2(a1.z, a1.w);
            *(uint4*)&As[row * 72 + s8 * 8] = u;
        }
        // stage x chunk fp32: 64 c x 64 px, coalesced along px
        #pragma unroll
        for (int i = 0; i < 4; ++i) {
            int idx = t + 256 * i;          // 0..1023
            int c = idx >> 4, p4 = (idx & 15) * 4;
            float4 vx = *(const float4*)&x[((size_t)b * CC + k0 + c) * HW + hw0 + p4];
            *(float4*)&xt32[c * 65 + p4] = vx;
        }
        __syncthreads();

        // transpose+convert into Bs: thread -> px = lane, 16 channels
        {
            const int px = lane;
            const int c0 = wv * 16;
            float f[16];
            #pragma unroll
            for (int j = 0; j < 16; ++j)
                f[j] = xt32[(c0 + j) * 65 + px];   // bank (c0+j+px)%32: 2-way
            uint4 w0, w1;
            w0.x = pack2(f[0],  f[1]);  w0.y = pack2(f[2],  f[3]);
            w0.z = pack2(f[4],  f[5]);  w0.w = pack2(f[6],  f[7]);
            w1.x = pack2(f[8],  f[9]);  w1.y = pack2(f[10], f[11]);
            w1.z = pack2(f[12], f[13]); w1.w = pack2(f[14], f[15]);
            const int lg0 = c0 >> 3, sw = px & 7;
            *(uint4*)&Bs[px * 64 + ((lg0     ^ sw) * 8)] = w0;
            *(uint4*)&Bs[px * 64 + (((lg0+1) ^ sw) * 8)] = w1;
        }
        __syncthreads();

        #pragma unroll
        for (int ks = 0; ks < 2; ++ks) {
            bf16x8 af[5], bf[4];
            #pragma unroll
            for (int i = 0; i < 5; ++i)
                af[i] = *(const bf16x8*)&As[((wv * 5 + i) * 16 + m16) * 72
                                            + ks * 32 + quad * 8];
            #pragma unroll
            for (int n = 0; n < 4; ++n) {
                int px = n * 16 + m16;
                int lg = ks * 4 + quad;
                bf[n] = *(const bf16x8*)&Bs[px * 64 + ((lg ^ (px & 7)) * 8)];
            }
            #pragma unroll
            for (int i = 0; i < 5; ++i)
                #pragma unroll
                for (int n = 0; n < 4; ++n)
                    acc[i][n] = __builtin_amdgcn_mfma_f32_16x16x32_bf16(
                        af[i], bf[n], acc[i][n], 0, 0, 0);
        }
    }

    // epilogue: D row = quad*4+reg, col = lane&15; biases direct from inputs
    #pragma unroll
    for (int i = 0; i < 5; ++i) {
        const int ob = (wv * 5 + i) * 16;        // 0..304, wave-uniform
        #pragma unroll
        for (int r = 0; r < 4; ++r) {
            const int orow = quad * 4 + r;
            const float bias = (ob < 32) ? bq[ob + orow]
                             : (ob < 64) ? bk[ob - 32 + orow]
                                         : bv[ob - 64 + orow];
            if (ob < 64) {                        // q or k, fp32
                float* dst = (ob < 32) ? q : k;
                int orel = (ob < 32) ? ob : ob - 32;
                size_t rowbase = ((size_t)b * CR + orel + orow) * HW;
                #pragma unroll
                for (int n = 0; n < 4; ++n)
                    dst[rowbase + hw0 + n * 16 + m16] = acc[i][n][r] + bias;
            } else {                              // v, bf16
                size_t rowbase = ((size_t)b * CC + (ob - 64) + orow) * HW;
                #pragma unroll
                for (int n = 0; n < 4; ++n)
                    vv[rowbase + hw0 + n * 16 + m16] = f2bf(acc[i][n][r] + bias);
            }
        }
    }
}

// ---------------------------------------------------------------------------
// K2: MERGED energies + softmax + apply + residual (R9 body).
// CHANGED vs R9: per-chunk residual-x prefetch — the two x float4 loads per
// chunk (the kernel's only HBM-compulsory reads) are issued at the TOP of
// the chunk, before vv staging + barriers, and consumed at the end. ~900cy
// HBM latency hides under stage+sync+LDS compute instead of being exposed
// at the tail. Layouts/arithmetic identical to R9 (odd strides 33/73/13).
// ---------------------------------------------------------------------------
__global__ __launch_bounds__(512) void attn_apply(
    const float* __restrict__ q_, const float* __restrict__ k_,
    const unsigned short* __restrict__ vv,
    const float* __restrict__ x, const float* __restrict__ gamma,
    float* __restrict__ out)
{
    struct PA {
        float qs[64][33];     //  8448 B
        float ks[3][64][33];  // 25344 B
        float es[64][9];      //  2304 B
    };
    struct PV {
        float vs[3][64][73];  // 56064 B  [row][ch][4 zero | 64 px | 4 zero | 1]
    };
    __shared__ union USM { PA a; PV v; } sm;    // 56064 B
    __shared__ float aws[64][13];               //  3328 B (persistent)

    const int h = blockIdx.x, b = blockIdx.y, t = threadIdx.x;

    // ---- stage q + 3 k-rows ----
    {
        const int cr = t >> 4, p4 = (t & 15) * 4;   // 512 threads = 32cr x 16px4
        float4 vq = *(const float4*)&q_[((size_t)b * CR + cr) * HW + h * WIMG + p4];
        sm.a.qs[p4 + 0][cr] = vq.x; sm.a.qs[p4 + 1][cr] = vq.y;
        sm.a.qs[p4 + 2][cr] = vq.z; sm.a.qs[p4 + 3][cr] = vq.w;
        #pragma unroll
        for (int r = 0; r < 3; ++r) {
            int hh = h + r - 1;
            float4 vk = make_float4(0.f, 0.f, 0.f, 0.f);
            if (hh >= 0 && hh < HIMG)
                vk = *(const float4*)&k_[((size_t)b * CR + cr) * HW + hh * WIMG + p4];
            sm.a.ks[r][p4 + 0][cr] = vk.x; sm.a.ks[r][p4 + 1][cr] = vk.y;
            sm.a.ks[r][p4 + 2][cr] = vk.z; sm.a.ks[r][p4 + 3][cr] = vk.w;
        }
    }
    __syncthreads();

    // ---- energies ----
    for (int id = t; id < 576; id += 512) {
        int px = id / 9, kk = id - px * 9;
        int di = kk / 3, dj = kk - di * 3;
        int hh = h + di - 1, ww = px + dj - 1;
        float e = 0.f;
        if (hh >= 0 && hh < HIMG && ww >= 0 && ww < WIMG) {
            float s = 0.f;
            #pragma unroll
            for (int c = 0; c < CR; ++c)
                s = fmaf(sm.a.qs[px][c], sm.a.ks[di][ww][c], s);
            e = s;
        }
        sm.a.es[px][kk] = e;
    }
    __syncthreads();

    // ---- softmax -> aws (LDS only) ----
    if (t < 64) {
        float m = sm.a.es[t][0];
        #pragma unroll
        for (int kk = 1; kk < 9; ++kk) m = fmaxf(m, sm.a.es[t][kk]);
        float ex[9]; float ssum = 0.f;
        #pragma unroll
        for (int kk = 0; kk < 9; ++kk) { ex[kk] = __expf(sm.a.es[t][kk] - m); ssum += ex[kk]; }
        float inv = 1.f / ssum;
        #pragma unroll
        for (int kk = 0; kk < 9; ++kk) aws[t][kk] = ex[kk] * inv;
    }
    __syncthreads();   // es reads done -> vs (overlapping a.*) may be written

    // ---- zero vs pads once ----
    if (t < 192) {
        int r = t / 64, c = t - r * 64;
        float* row = &sm.v.vs[r][c][0];
        row[0] = 0.f; row[1] = 0.f; row[2] = 0.f; row[3] = 0.f;
        row[68] = 0.f; row[69] = 0.f; row[70] = 0.f; row[71] = 0.f;
    }

    const int px0 = (t & 15) * 4;
    const int cl  = t >> 4;                 // 0..31
    const float g = gamma[0];
    float w[4][9];
    #pragma unroll
    for (int i = 0; i < 4; ++i)
        #pragma unroll
        for (int kk = 0; kk < 9; ++kk) w[i][kk] = aws[px0 + i][kk];

    // ---- 4 chunks of 64 channels ----
    for (int cb = 0; cb < 4; ++cb) {
        // residual-x prefetch: issue FIRST, consume last (hides HBM latency)
        size_t base0 = ((size_t)b * CC + cb * 64 + cl) * HW + h * WIMG + px0;
        size_t base1 = base0 + (size_t)32 * HW;
        float4 xa0 = *(const float4*)&x[base0];
        float4 xa1 = *(const float4*)&x[base1];

        if (cb) __syncthreads();            // protect vs reuse
        #pragma unroll
        for (int i = 0; i < 6; ++i) {
            int idx = t + 512 * i;          // 0..3071
            int p4 = (idx & 15) * 4, c = (idx >> 4) & 63, r = idx >> 10;
            int hh = h + r - 1;
            float4 val = make_float4(0.f, 0.f, 0.f, 0.f);
            if (hh >= 0 && hh < HIMG) {
                ushort4 u = *(const ushort4*)&vv[((size_t)b * CC + cb * 64 + c) * HW
                                                 + hh * WIMG + p4];
                val = make_float4(bf2f(u.x), bf2f(u.y), bf2f(u.z), bf2f(u.w));
            }
            float* dstp = &sm.v.vs[r][c][4 + p4];
            dstp[0] = val.x; dstp[1] = val.y; dstp[2] = val.z; dstp[3] = val.w;
        }
        __syncthreads();

        #pragma unroll
        for (int ci = 0; ci < 2; ++ci) {
            int c = cl + 32 * ci;
            float a0 = 0.f, a1 = 0.f, a2 = 0.f, a3 = 0.f;
            #pragma unroll
            for (int r = 0; r < 3; ++r) {
                const float* row = &sm.v.vs[r][c][0];
                float lft = row[3 + px0];
                float c0  = row[4 + px0];
                float c1  = row[5 + px0];
                float c2  = row[6 + px0];
                float c3  = row[7 + px0];
                float rgt = row[8 + px0];
                int r3 = r * 3;
                a0 = fmaf(w[0][r3], lft, fmaf(w[0][r3+1], c0, fmaf(w[0][r3+2], c1, a0)));
                a1 = fmaf(w[1][r3], c0,  fmaf(w[1][r3+1], c1, fmaf(w[1][r3+2], c2, a1)));
                a2 = fmaf(w[2][r3], c1,  fmaf(w[2][r3+1], c2, fmaf(w[2][r3+2], c3, a2)));
                a3 = fmaf(w[3][r3], c2,  fmaf(w[3][r3+1], c3, fmaf(w[3][r3+2], rgt, a3)));
            }
            float4 xa = ci ? xa1 : xa0;
            size_t base = ci ? base1 : base0;
            float4 o;
            o.x = fmaf(g, a0, xa.x); o.y = fmaf(g, a1, xa.y);
            o.z = fmaf(g, a2, xa.z); o.w = fmaf(g, a3, xa.w);
            *(float4*)&out[base] = o;
        }
    }
}

extern "C" void kernel_launch(void* const* d_in, const int* in_sizes, int n_in,
                              void* d_out, int out_size, void* d_ws, size_t ws_size,
                              hipStream_t stream)
{
    const float* x     = (const float*)d_in[0];
    const float* Wq    = (const float*)d_in[1];
    const float* bq    = (const float*)d_in[2];
    const float* Wk    = (const float*)d_in[3];
    const float* bk    = (const float*)d_in[4];
    const float* Wv    = (const float*)d_in[5];
    const float* bv    = (const float*)d_in[6];
    const float* gamma = (const float*)d_in[7];
    float* out = (float*)d_out;

    float* q  = (float*)d_ws;                                  //  4.19 MB
    float* k  = q + (size_t)B_ * CR * HW;                      //  4.19 MB
    unsigned short* vv = (unsigned short*)(k + (size_t)B_ * CR * HW); // 16.78 MB

    proj_gemm<<<dim3(HW / 64, B_), 256, 0, stream>>>(
        Wq, bq, Wk, bk, Wv, bv, x, q, k, vv);
    attn_apply<<<dim3(HIMG, B_), 512, 0, stream>>>(q, k, vv, x, gamma, out);
}

// Round 11
// 125.614 us; speedup vs baseline: 1.1279x; 1.0208x over previous
//
#include <hip/hip_runtime.h>

#define HW   4096
#define HIMG 64
#define WIMG 64
#define CC   256
#define CR   32
#define B_   8

typedef __attribute__((ext_vector_type(8))) short bf16x8;
typedef __attribute__((ext_vector_type(4))) float f32x4;

__device__ inline unsigned short f2bf(float f) {
    union { float f; unsigned u; } v; v.f = f;
    return (unsigned short)((v.u + 0x8000u) >> 16);
}
__device__ inline float bf2f(unsigned short h) {
    union { unsigned u; float f; } v; v.u = ((unsigned)h) << 16; return v.f;
}
__device__ inline unsigned pack2(float a, float b) {
    return (unsigned)f2bf(a) | ((unsigned)f2bf(b) << 16);
}

// ---------------------------------------------------------------------------
// K1: fused transpose+convert+GEMM (R10 body).
// CHANGED vs R10 (single variable): q and k are stored to HBM as bf16
// (f2bf of the same fp32 value) -> epilogue write bytes halved.  The energy
// dot in K2 runs on bf16-rounded q/k in fp32 accumulation; error ~0.3% of
// |energy|, orders below the 0.108 threshold.
// ---------------------------------------------------------------------------
__global__ __launch_bounds__(256) void proj_gemm(
    const float* __restrict__ Wq, const float* __restrict__ bq,
    const float* __restrict__ Wk, const float* __restrict__ bk,
    const float* __restrict__ Wv, const float* __restrict__ bv,
    const float* __restrict__ x,
    unsigned short* __restrict__ q, unsigned short* __restrict__ k,
    unsigned short* __restrict__ vv)
{
    __shared__ unsigned short As[320 * 72];
    __shared__ float          xt32[64 * 65];
    __shared__ unsigned short Bs[64 * 64];

    const int b   = blockIdx.y;
    const int hw0 = blockIdx.x * 64;
    const int t    = threadIdx.x;
    const int lane = t & 63, wv = t >> 6;
    const int m16  = lane & 15, quad = lane >> 4;

    f32x4 acc[5][4];
    #pragma unroll
    for (int i = 0; i < 5; ++i)
        #pragma unroll
        for (int n = 0; n < 4; ++n)
            acc[i][n] = (f32x4){0.f, 0.f, 0.f, 0.f};

    for (int kc = 0; kc < 4; ++kc) {
        const int k0 = kc * 64;
        if (kc) __syncthreads();            // protect As/xt32/Bs reuse

        // stage A: 320 rows x 64 ch, fp32 source -> bf16 inline (same f2bf)
        #pragma unroll
        for (int i = 0; i < 10; ++i) {
            int idx = t + 256 * i;          // 0..2559
            int row = idx >> 3, s8 = idx & 7;
            const float* wsrc = (row < 32) ? &Wq[row * CC]
                              : (row < 64) ? &Wk[(row - 32) * CC]
                                           : &Wv[(row - 64) * CC];
            float4 a0 = *(const float4*)&wsrc[k0 + s8 * 8];
            float4 a1 = *(const float4*)&wsrc[k0 + s8 * 8 + 4];
            uint4 u;
            u.x = pack2(a0.x, a0.y); u.y = pack2(a0.z, a0.w);
            u.z = pack2(a1.x, a1.y); u.w = pack2(a1.z, a1.w);
            *(uint4*)&As[row * 72 + s8 * 8] = u;
        }
        // stage x chunk fp32: 64 c x 64 px, coalesced along px
        #pragma unroll
        for (int i = 0; i < 4; ++i) {
            int idx = t + 256 * i;          // 0..1023
            int c = idx >> 4, p4 = (idx & 15) * 4;
            float4 vx = *(const float4*)&x[((size_t)b * CC + k0 + c) * HW + hw0 + p4];
            *(float4*)&xt32[c * 65 + p4] = vx;
        }
        __syncthreads();

        // transpose+convert into Bs: thread -> px = lane, 16 channels
        {
            const int px = lane;
            const int c0 = wv * 16;
            float f[16];
            #pragma unroll
            for (int j = 0; j < 16; ++j)
                f[j] = xt32[(c0 + j) * 65 + px];   // bank (c0+j+px)%32: 2-way
            uint4 w0, w1;
            w0.x = pack2(f[0],  f[1]);  w0.y = pack2(f[2],  f[3]);
            w0.z = pack2(f[4],  f[5]);  w0.w = pack2(f[6],  f[7]);
            w1.x = pack2(f[8],  f[9]);  w1.y = pack2(f[10], f[11]);
            w1.z = pack2(f[12], f[13]); w1.w = pack2(f[14], f[15]);
            const int lg0 = c0 >> 3, sw = px & 7;
            *(uint4*)&Bs[px * 64 + ((lg0     ^ sw) * 8)] = w0;
            *(uint4*)&Bs[px * 64 + (((lg0+1) ^ sw) * 8)] = w1;
        }
        __syncthreads();

        #pragma unroll
        for (int ks = 0; ks < 2; ++ks) {
            bf16x8 af[5], bf[4];
            #pragma unroll
            for (int i = 0; i < 5; ++i)
                af[i] = *(const bf16x8*)&As[((wv * 5 + i) * 16 + m16) * 72
                                            + ks * 32 + quad * 8];
            #pragma unroll
            for (int n = 0; n < 4; ++n) {
                int px = n * 16 + m16;
                int lg = ks * 4 + quad;
                bf[n] = *(const bf16x8*)&Bs[px * 64 + ((lg ^ (px & 7)) * 8)];
            }
            #pragma unroll
            for (int i = 0; i < 5; ++i)
                #pragma unroll
                for (int n = 0; n < 4; ++n)
                    acc[i][n] = __builtin_amdgcn_mfma_f32_16x16x32_bf16(
                        af[i], bf[n], acc[i][n], 0, 0, 0);
        }
    }

    // epilogue: D row = quad*4+reg, col = lane&15; biases direct from inputs
    #pragma unroll
    for (int i = 0; i < 5; ++i) {
        const int ob = (wv * 5 + i) * 16;        // 0..304, wave-uniform
        #pragma unroll
        for (int r = 0; r < 4; ++r) {
            const int orow = quad * 4 + r;
            const float bias = (ob < 32) ? bq[ob + orow]
                             : (ob < 64) ? bk[ob - 32 + orow]
                                         : bv[ob - 64 + orow];
            if (ob < 64) {                        // q or k -> bf16
                unsigned short* dst = (ob < 32) ? q : k;
                int orel = (ob < 32) ? ob : ob - 32;
                size_t rowbase = ((size_t)b * CR + orel + orow) * HW;
                #pragma unroll
                for (int n = 0; n < 4; ++n)
                    dst[rowbase + hw0 + n * 16 + m16] = f2bf(acc[i][n][r] + bias);
            } else {                              // v, bf16
                size_t rowbase = ((size_t)b * CC + (ob - 64) + orow) * HW;
                #pragma unroll
                for (int n = 0; n < 4; ++n)
                    vv[rowbase + hw0 + n * 16 + m16] = f2bf(acc[i][n][r] + bias);
            }
        }
    }
}

// ---------------------------------------------------------------------------
// K2: MERGED energies + softmax + apply + residual (R10 body).
// CHANGED vs R10 (same single variable): q/k staged from bf16 HBM (ushort4
// loads, bf2f to fp32 in LDS).  qs/ks layouts, energies, softmax, apply and
// residual-prefetch all byte-identical to R10.
// ---------------------------------------------------------------------------
__global__ __launch_bounds__(512) void attn_apply(
    const unsigned short* __restrict__ q_, const unsigned short* __restrict__ k_,
    const unsigned short* __restrict__ vv,
    const float* __restrict__ x, const float* __restrict__ gamma,
    float* __restrict__ out)
{
    struct PA {
        float qs[64][33];     //  8448 B
        float ks[3][64][33];  // 25344 B
        float es[64][9];      //  2304 B
    };
    struct PV {
        float vs[3][64][73];  // 56064 B  [row][ch][4 zero | 64 px | 4 zero | 1]
    };
    __shared__ union USM { PA a; PV v; } sm;    // 56064 B
    __shared__ float aws[64][13];               //  3328 B (persistent)

    const int h = blockIdx.x, b = blockIdx.y, t = threadIdx.x;

    // ---- stage q + 3 k-rows (bf16 source) ----
    {
        const int cr = t >> 4, p4 = (t & 15) * 4;   // 512 threads = 32cr x 16px4
        ushort4 uq = *(const ushort4*)&q_[((size_t)b * CR + cr) * HW + h * WIMG + p4];
        sm.a.qs[p4 + 0][cr] = bf2f(uq.x); sm.a.qs[p4 + 1][cr] = bf2f(uq.y);
        sm.a.qs[p4 + 2][cr] = bf2f(uq.z); sm.a.qs[p4 + 3][cr] = bf2f(uq.w);
        #pragma unroll
        for (int r = 0; r < 3; ++r) {
            int hh = h + r - 1;
            ushort4 uk = make_ushort4(0, 0, 0, 0);
            if (hh >= 0 && hh < HIMG)
                uk = *(const ushort4*)&k_[((size_t)b * CR + cr) * HW + hh * WIMG + p4];
            sm.a.ks[r][p4 + 0][cr] = bf2f(uk.x); sm.a.ks[r][p4 + 1][cr] = bf2f(uk.y);
            sm.a.ks[r][p4 + 2][cr] = bf2f(uk.z); sm.a.ks[r][p4 + 3][cr] = bf2f(uk.w);
        }
    }
    __syncthreads();

    // ---- energies ----
    for (int id = t; id < 576; id += 512) {
        int px = id / 9, kk = id - px * 9;
        int di = kk / 3, dj = kk - di * 3;
        int hh = h + di - 1, ww = px + dj - 1;
        float e = 0.f;
        if (hh >= 0 && hh < HIMG && ww >= 0 && ww < WIMG) {
            float s = 0.f;
            #pragma unroll
            for (int c = 0; c < CR; ++c)
                s = fmaf(sm.a.qs[px][c], sm.a.ks[di][ww][c], s);
            e = s;
        }
        sm.a.es[px][kk] = e;
    }
    __syncthreads();

    // ---- softmax -> aws (LDS only) ----
    if (t < 64) {
        float m = sm.a.es[t][0];
        #pragma unroll
        for (int kk = 1; kk < 9; ++kk) m = fmaxf(m, sm.a.es[t][kk]);
        float ex[9]; float ssum = 0.f;
        #pragma unroll
        for (int kk = 0; kk < 9; ++kk) { ex[kk] = __expf(sm.a.es[t][kk] - m); ssum += ex[kk]; }
        float inv = 1.f / ssum;
        #pragma unroll
        for (int kk = 0; kk < 9; ++kk) aws[t][kk] = ex[kk] * inv;
    }
    __syncthreads();   // es reads done -> vs (overlapping a.*) may be written

    // ---- zero vs pads once ----
    if (t < 192) {
        int r = t / 64, c = t - r * 64;
        float* row = &sm.v.vs[r][c][0];
        row[0] = 0.f; row[1] = 0.f; row[2] = 0.f; row[3] = 0.f;
        row[68] = 0.f; row[69] = 0.f; row[70] = 0.f; row[71] = 0.f;
    }

    const int px0 = (t & 15) * 4;
    const int cl  = t >> 4;                 // 0..31
    const float g = gamma[0];
    float w[4][9];
    #pragma unroll
    for (int i = 0; i < 4; ++i)
        #pragma unroll
        for (int kk = 0; kk < 9; ++kk) w[i][kk] = aws[px0 + i][kk];

    // ---- 4 chunks of 64 channels ----
    for (int cb = 0; cb < 4; ++cb) {
        // residual-x prefetch: issue FIRST, consume last (hides HBM latency)
        size_t base0 = ((size_t)b * CC + cb * 64 + cl) * HW + h * WIMG + px0;
        size_t base1 = base0 + (size_t)32 * HW;
        float4 xa0 = *(const float4*)&x[base0];
        float4 xa1 = *(const float4*)&x[base1];

        if (cb) __syncthreads();            // protect vs reuse
        #pragma unroll
        for (int i = 0; i < 6; ++i) {
            int idx = t + 512 * i;          // 0..3071
            int p4 = (idx & 15) * 4, c = (idx >> 4) & 63, r = idx >> 10;
            int hh = h + r - 1;
            float4 val = make_float4(0.f, 0.f, 0.f, 0.f);
            if (hh >= 0 && hh < HIMG) {
                ushort4 u = *(const ushort4*)&vv[((size_t)b * CC + cb * 64 + c) * HW
                                                 + hh * WIMG + p4];
                val = make_float4(bf2f(u.x), bf2f(u.y), bf2f(u.z), bf2f(u.w));
            }
            float* dstp = &sm.v.vs[r][c][4 + p4];
            dstp[0] = val.x; dstp[1] = val.y; dstp[2] = val.z; dstp[3] = val.w;
        }
        __syncthreads();

        #pragma unroll
        for (int ci = 0; ci < 2; ++ci) {
            int c = cl + 32 * ci;
            float a0 = 0.f, a1 = 0.f, a2 = 0.f, a3 = 0.f;
            #pragma unroll
            for (int r = 0; r < 3; ++r) {
                const float* row = &sm.v.vs[r][c][0];
                float lft = row[3 + px0];
                float c0  = row[4 + px0];
                float c1  = row[5 + px0];
                float c2  = row[6 + px0];
                float c3  = row[7 + px0];
                float rgt = row[8 + px0];
                int r3 = r * 3;
                a0 = fmaf(w[0][r3], lft, fmaf(w[0][r3+1], c0, fmaf(w[0][r3+2], c1, a0)));
                a1 = fmaf(w[1][r3], c0,  fmaf(w[1][r3+1], c1, fmaf(w[1][r3+2], c2, a1)));
                a2 = fmaf(w[2][r3], c1,  fmaf(w[2][r3+1], c2, fmaf(w[2][r3+2], c3, a2)));
                a3 = fmaf(w[3][r3], c2,  fmaf(w[3][r3+1], c3, fmaf(w[3][r3+2], rgt, a3)));
            }
            float4 xa = ci ? xa1 : xa0;
            size_t base = ci ? base1 : base0;
            float4 o;
            o.x = fmaf(g, a0, xa.x); o.y = fmaf(g, a1, xa.y);
            o.z = fmaf(g, a2, xa.z); o.w = fmaf(g, a3, xa.w);
            *(float4*)&out[base] = o;
        }
    }
}

extern "C" void kernel_launch(void* const* d_in, const int* in_sizes, int n_in,
                              void* d_out, int out_size, void* d_ws, size_t ws_size,
                              hipStream_t stream)
{
    const float* x     = (const float*)d_in[0];
    const float* Wq    = (const float*)d_in[1];
    const float* bq    = (const float*)d_in[2];
    const float* Wk    = (const float*)d_in[3];
    const float* bk    = (const float*)d_in[4];
    const float* Wv    = (const float*)d_in[5];
    const float* bv    = (const float*)d_in[6];
    const float* gamma = (const float*)d_in[7];
    float* out = (float*)d_out;

    unsigned short* q  = (unsigned short*)d_ws;                //  2.10 MB
    unsigned short* k  = q + (size_t)B_ * CR * HW;             //  2.10 MB
    unsigned short* vv = k + (size_t)B_ * CR * HW;             // 16.78 MB

    proj_gemm<<<dim3(HW / 64, B_), 256, 0, stream>>>(
        Wq, bq, Wk, bk, Wv, bv, x, q, k, vv);
    attn_apply<<<dim3(HIMG, B_), 512, 0, stream>>>(q, k, vv, x, gamma, out);
}